// Round 8
// baseline (436.944 us; speedup 1.0000x reference)
//
#include <hip/hip_runtime.h>
#include <hip/hip_fp16.h>

#define F_IN  128
#define F_HID 8
#define F_OUT 16

#define SBSH  9                 // coarse bucket = 512 consecutive dst nodes
#define SBW   (1 << SBSH)
#define MAXB  400               // supports N <= 204800
#define BIN_CAP  32             // LDS entries per bucket (stage_bin)
#define FLUSH_G  16             // flush granularity (16 ints = 64B line)

// edge_index arrives as int32 [2][E].
// Session laws: (1) scattered 4B global stores/atomics cost ~64B cross-XCD
// writeback -> all scatters are LDS-write-combined contiguous runs;
// (2) gather/scatter kernels need >=2 blocks/CU and plenty of waves;
// (3) fp16 g (3.2MB) is L2-resident -> gathers are ~200-550cy; single-use
// streams (csr, x, ei) are non-temporal; (4) per-node epilogues fuse into
// aggregates; (5) bucket regions are FIXED-CAP (avg+6%);
// (6) cursor-reserving atomics must be issued by MANY CONCURRENT THREADS;
// a per-wave serial dependent chain (atomic->shfl->copy->next) serializes
// ~400K contended RMWs -> 8x blowup (R5/R6). Same-address atomic
// serialization shows as ALL-PIPES-IDLE (VALU ~2%, HBM ~2%).
// R3 LESSON: aggregate gather loops are pinned by per-CU outstanding-line
// capacity, not per-wave ILP (three loop shapes all ~74us).
// R8: stage_bin polish ONLY, structure preserved: flush-NEWEST-16 (no
// compaction copy, compile-time unroll-16 -> 16 independent ds_reads),
// NT edge loads, init_gcur -> hipMemsetAsync (relative cursors, -1 dispatch).

typedef float f32x4 __attribute__((ext_vector_type(4)));
typedef int   i32x4 __attribute__((ext_vector_type(4)));

// LDS write-combined binning: stage[...] = (src<<9)|(dst&511), bucket-grouped.
// 512 threads/block; NT int4 edge loads; bin_buf slots swizzled (pos+b)&31.
// gcur[b] is RELATIVE fill (memset-0 init); region base = b*cap.
__global__ __launch_bounds__(512) void stage_bin(const int* __restrict__ ei,
                                                 int* __restrict__ gcur,
                                                 int* __restrict__ stage,
                                                 int E, int B, int cap, int per_block) {
    __shared__ int bin_cnt[MAXB];
    __shared__ int bin_buf[MAXB * BIN_CAP];   // ~50KB
    for (int i = threadIdx.x; i < B; i += blockDim.x) bin_cnt[i] = 0;
    __syncthreads();
    const bool vec = ((E & 3) == 0);
    int base = blockIdx.x * per_block;
    int end  = min(E, base + per_block);
    for (int it = base; it < end; it += (int)blockDim.x * 4) {
        int e = it + (int)threadIdx.x * 4;
        int sv[4], dv[4], m4 = 0;
        if (vec && e + 3 < end) {
            i32x4 s4 = __builtin_nontemporal_load((const i32x4*)(ei + e));
            i32x4 d4 = __builtin_nontemporal_load((const i32x4*)(ei + E + e));
            sv[0] = s4.x; sv[1] = s4.y; sv[2] = s4.z; sv[3] = s4.w;
            dv[0] = d4.x; dv[1] = d4.y; dv[2] = d4.z; dv[3] = d4.w;
            m4 = 4;
        } else {
            for (int q = 0; e + q < end && q < 4; q++) { sv[q] = ei[e + q]; dv[q] = ei[E + e + q]; m4++; }
        }
        for (int q = 0; q < m4; q++) {
            int b   = dv[q] >> SBSH;
            int val = (sv[q] << SBSH) | (dv[q] & (SBW - 1));
            int pos = atomicAdd(&bin_cnt[b], 1);
            if (pos < BIN_CAP) {
                bin_buf[b * BIN_CAP + ((pos + b) & (BIN_CAP - 1))] = val;
            } else {                                  // overflow (rare): direct store
                int gp = b * cap + atomicAdd(&gcur[b], 1);
                stage[gp] = val;
            }
        }
        __syncthreads();
        // flush-NEWEST-16: leftovers [0, c-16) keep their slots -> no compaction.
        // New arrivals fill pos c-16..31; pos>=32 diverts to overflow before
        // wrapping onto live slots. Cursor atomics: one per bucket, issued by
        // ~391 CONCURRENT threads (law 6).
        for (int b2 = threadIdx.x; b2 < B; b2 += blockDim.x) {
            int c = min(bin_cnt[b2], BIN_CAP);
            while (c >= FLUSH_G) {
                int s0 = c - FLUSH_G;
                int r  = b2 * cap + atomicAdd(&gcur[b2], FLUSH_G);
#pragma unroll
                for (int k = 0; k < FLUSH_G; k++)     // 16 independent ds_reads
                    stage[r + k] = bin_buf[b2 * BIN_CAP + ((s0 + k + b2) & (BIN_CAP - 1))];
                c = s0;
            }
            bin_cnt[b2] = c;
        }
        __syncthreads();
    }
    for (int b2 = threadIdx.x; b2 < B; b2 += blockDim.x) {   // final flush (c <= 15)
        int c = min(bin_cnt[b2], BIN_CAP);
        if (c > 0) {
            int r = b2 * cap + atomicAdd(&gcur[b2], c);
            for (int k = 0; k < c; k++)
                stage[r + k] = bin_buf[b2 * BIN_CAP + ((k + b2) & (BIN_CAP - 1))];
        }
    }
}

// one block (1024 thr) per bucket: LDS per-node hist from stage -> cnt/dis,
// scan -> row_start, then scatter src into the bucket's warm CSR segment.
__global__ __launch_bounds__(1024) void scatter_csr(const int* __restrict__ stage,
                                                    const int* __restrict__ gcur,
                                                    int cap,
                                                    int* __restrict__ cnt,
                                                    float* __restrict__ dis,
                                                    int* __restrict__ row_start,
                                                    int* __restrict__ csr, int n) {
    __shared__ int s0[SBW], s1[SBW];
    int b  = blockIdx.x;
    int nb = b << SBSH;
    int i  = threadIdx.x;          // 0..1023
    if (i < SBW) s0[i] = 0;
    __syncthreads();
    int base = b * cap;
    int num  = gcur[b];            // relative fill count
    for (int k = i; k < num; k += 1024)
        atomicAdd(&s0[stage[base + k] & (SBW - 1)], 1);
    __syncthreads();
    int c = (i < SBW) ? s0[i] : 0;
    if (i < SBW && nb + i < n) { cnt[nb + i] = c; dis[nb + i] = rsqrtf((float)(c + 1)); }
    int* src = s0; int* dst = s1;
    for (int off = 1; off < SBW; off <<= 1) {       // Hillis-Steele inclusive scan
        if (i < SBW) dst[i] = src[i] + ((i >= off) ? src[i - off] : 0);
        __syncthreads();
        int* t = src; src = dst; dst = t;
    }
    if (i < SBW) {
        int e = base + src[i] - c;                   // exclusive scan (csr shares region layout)
        if (nb + i < n) row_start[nb + i] = e;
        dst[i] = e;                                  // dst becomes the cursor array
    }
    __syncthreads();
    for (int k = i; k < num; k += 1024) {
        int v = stage[base + k];
        int pos = atomicAdd(&dst[v & (SBW - 1)], 1);
        csr[pos] = v >> SBSH;
    }
}

// ---------------- layer-1 GEMM: g1 = (x @ W1) * dis, stored fp16 ----------------
// 8 lanes/node: 128B contiguous NT reads per group step; W1 transposed in LDS;
// shfl_xor width-8 reduce; lane0 16B store. (verified R1-R4)
__global__ __launch_bounds__(256) void gemm1(const float* __restrict__ x,
                                             const float* __restrict__ W1,
                                             const float* __restrict__ dis,
                                             __half* __restrict__ g1, int n) {
    __shared__ float w2[F_HID * F_IN];   // [f][k] transposed, 4KB
    for (int i = threadIdx.x; i < F_HID * F_IN; i += blockDim.x) {
        int f = i >> 7, k = i & (F_IN - 1);
        w2[i] = W1[k * F_HID + f];
    }
    __syncthreads();
    int t = blockIdx.x * blockDim.x + threadIdx.x;
    int node = t >> 3, l = t & 7;
    if (node >= n) return;
    const f32x4* xr = (const f32x4*)(x + (size_t)node * F_IN);
    float acc[F_HID];
#pragma unroll
    for (int f = 0; f < F_HID; f++) acc[f] = 0.0f;
#pragma unroll
    for (int it = 0; it < 4; it++) {
        int j = l + it * 8;                       // this lane's float4 index
        f32x4 v = __builtin_nontemporal_load(xr + j);
#pragma unroll
        for (int f = 0; f < F_HID; f++) {
            const float* wf = &w2[f * F_IN + j * 4];
            acc[f] += v[0] * wf[0] + v[1] * wf[1] + v[2] * wf[2] + v[3] * wf[3];
        }
    }
#pragma unroll
    for (int f = 0; f < F_HID; f++) {             // reduce across the 8 lanes
        acc[f] += __shfl_xor(acc[f], 1);
        acc[f] += __shfl_xor(acc[f], 2);
        acc[f] += __shfl_xor(acc[f], 4);
    }
    if (l == 0) {
        float d = dis[node];
        __half2 h[4];
#pragma unroll
        for (int p = 0; p < 4; p++) h[p] = __floats2half2_rn(acc[2 * p] * d, acc[2 * p + 1] * d);
        *(uint4*)(g1 + (size_t)node * F_HID) = *(uint4*)h;   // 16B store
    }
}

// ---------------- layer-1 aggregate + bias + ReLU + xdis -> g2 (fp16) ----------------
// 4 lanes/node, lane l owns features {2l,2l+1} as one half2 (unchanged from R4).
__global__ __launch_bounds__(256) void aggregate_relu(const int* __restrict__ csr,
                                                      const int* __restrict__ row_start,
                                                      const int* __restrict__ cnt,
                                                      const float* __restrict__ dis,
                                                      const float* __restrict__ b1,
                                                      const __half* __restrict__ gin,
                                                      __half* __restrict__ gout, int n) {
    int t = blockIdx.x * blockDim.x + threadIdx.x;
    int node = t >> 2;
    int l = t & 3;
    if (node >= n) return;
    const __half2* g2 = (const __half2*)gin;      // half2 index = src*4 + l
    int beg = row_start[node];
    int c   = cnt[node];
    float2 acc = __half22float2(g2[(unsigned)node * 4 + l]);   // self-loop
    int j = 0;
    int cm8 = c & ~7;
    for (; j < cm8; j += 8) {
        int va = __builtin_nontemporal_load(csr + beg + j + l);
        int vb = __builtin_nontemporal_load(csr + beg + j + 4 + l);
        int s0 = __shfl(va, 0, 4), s1 = __shfl(va, 1, 4);
        int s2 = __shfl(va, 2, 4), s3 = __shfl(va, 3, 4);
        int s4 = __shfl(vb, 0, 4), s5 = __shfl(vb, 1, 4);
        int s6 = __shfl(vb, 2, 4), s7 = __shfl(vb, 3, 4);
        __half2 h0 = g2[(unsigned)s0 * 4 + l];    // 8 independent 4B gathers
        __half2 h1 = g2[(unsigned)s1 * 4 + l];
        __half2 h2 = g2[(unsigned)s2 * 4 + l];
        __half2 h3 = g2[(unsigned)s3 * 4 + l];
        __half2 h4 = g2[(unsigned)s4 * 4 + l];
        __half2 h5 = g2[(unsigned)s5 * 4 + l];
        __half2 h6 = g2[(unsigned)s6 * 4 + l];
        __half2 h7 = g2[(unsigned)s7 * 4 + l];
        float2 f0 = __half22float2(h0), f1 = __half22float2(h1);
        float2 f2 = __half22float2(h2), f3 = __half22float2(h3);
        float2 f4 = __half22float2(h4), f5 = __half22float2(h5);
        float2 f6 = __half22float2(h6), f7 = __half22float2(h7);
        acc.x += ((f0.x + f1.x) + (f2.x + f3.x)) + ((f4.x + f5.x) + (f6.x + f7.x));
        acc.y += ((f0.y + f1.y) + (f2.y + f3.y)) + ((f4.y + f5.y) + (f6.y + f7.y));
    }
    for (; j < c; j++) {
        int s = __builtin_nontemporal_load(csr + beg + j);
        float2 a = __half22float2(g2[(unsigned)s * 4 + l]);
        acc.x += a.x; acc.y += a.y;
    }
    float d = dis[node];
    float2 bv = *(const float2*)(b1 + 2 * l);
    float rx = fmaxf(fmaf(acc.x, d, bv.x), 0.0f) * d;
    float ry = fmaxf(fmaf(acc.y, d, bv.y), 0.0f) * d;
    ((__half2*)gout)[(unsigned)node * 4 + l] = __floats2half2_rn(rx, ry);  // 256B/wave
}

// ---------------- layer-2 aggregate + W2/b2 -> out ----------------
__global__ __launch_bounds__(256) void aggregate_out(const int* __restrict__ csr,
                                                     const int* __restrict__ row_start,
                                                     const int* __restrict__ cnt,
                                                     const float* __restrict__ dis,
                                                     const float* __restrict__ W2,
                                                     const float* __restrict__ b2,
                                                     const __half* __restrict__ gin,
                                                     float* __restrict__ out, int n) {
    int t = blockIdx.x * blockDim.x + threadIdx.x;
    int node = t >> 2;
    int l = t & 3;
    if (node >= n) return;
    const __half2* g2 = (const __half2*)gin;
    int beg = row_start[node];
    int c   = cnt[node];
    float2 acc = __half22float2(g2[(unsigned)node * 4 + l]);   // self-loop
    int j = 0;
    int cm8 = c & ~7;
    for (; j < cm8; j += 8) {
        int va = __builtin_nontemporal_load(csr + beg + j + l);
        int vb = __builtin_nontemporal_load(csr + beg + j + 4 + l);
        int s0 = __shfl(va, 0, 4), s1 = __shfl(va, 1, 4);
        int s2 = __shfl(va, 2, 4), s3 = __shfl(va, 3, 4);
        int s4 = __shfl(vb, 0, 4), s5 = __shfl(vb, 1, 4);
        int s6 = __shfl(vb, 2, 4), s7 = __shfl(vb, 3, 4);
        __half2 h0 = g2[(unsigned)s0 * 4 + l];
        __half2 h1 = g2[(unsigned)s1 * 4 + l];
        __half2 h2 = g2[(unsigned)s2 * 4 + l];
        __half2 h3 = g2[(unsigned)s3 * 4 + l];
        __half2 h4 = g2[(unsigned)s4 * 4 + l];
        __half2 h5 = g2[(unsigned)s5 * 4 + l];
        __half2 h6 = g2[(unsigned)s6 * 4 + l];
        __half2 h7 = g2[(unsigned)s7 * 4 + l];
        float2 f0 = __half22float2(h0), f1 = __half22float2(h1);
        float2 f2 = __half22float2(h2), f3 = __half22float2(h3);
        float2 f4 = __half22float2(h4), f5 = __half22float2(h5);
        float2 f6 = __half22float2(h6), f7 = __half22float2(h7);
        acc.x += ((f0.x + f1.x) + (f2.x + f3.x)) + ((f4.x + f5.x) + (f6.x + f7.x));
        acc.y += ((f0.y + f1.y) + (f2.y + f3.y)) + ((f4.y + f5.y) + (f6.y + f7.y));
    }
    for (; j < c; j++) {
        int s = __builtin_nontemporal_load(csr + beg + j);
        float2 a = __half22float2(g2[(unsigned)s * 4 + l]);
        acc.x += a.x; acc.y += a.y;
    }
    float d = dis[node];
    float ax = acc.x * d, ay = acc.y * d;         // a[2l], a[2l+1]
    float4 o = ((const float4*)b2)[l];            // outputs 4l..4l+3
#pragma unroll
    for (int s = 0; s < 4; s++) {
        float axs = __shfl(ax, s, 4);             // a[2s]
        float ays = __shfl(ay, s, 4);             // a[2s+1]
        float4 w0 = ((const float4*)W2)[(2 * s) * 4 + l];       // W2[2s][4l..4l+3]
        float4 w1 = ((const float4*)W2)[(2 * s + 1) * 4 + l];   // W2[2s+1][4l..4l+3]
        o.x = fmaf(axs, w0.x, fmaf(ays, w1.x, o.x));
        o.y = fmaf(axs, w0.y, fmaf(ays, w1.y, o.y));
        o.z = fmaf(axs, w0.z, fmaf(ays, w1.z, o.z));
        o.w = fmaf(axs, w0.w, fmaf(ays, w1.w, o.w));
    }
    *(float4*)(out + (size_t)node * F_OUT + 4 * l) = o;         // 1KB/wave contiguous
}

extern "C" void kernel_launch(void* const* d_in, const int* in_sizes, int n_in,
                              void* d_out, int out_size, void* d_ws, size_t ws_size,
                              hipStream_t stream) {
    const float* x  = (const float*)d_in[0];
    const int*   ei = (const int*)d_in[1];
    const float* W1 = (const float*)d_in[2];
    const float* b1 = (const float*)d_in[3];
    const float* W2 = (const float*)d_in[4];
    const float* b2 = (const float*)d_in[5];
    float* out = (float*)d_out;

    const int N = in_sizes[0] / F_IN;
    const int E = in_sizes[1] / 2;
    const int B = (N + SBW - 1) >> SBSH;   // 391 for N=200000

    // fixed bucket capacity: avg + ~6%, rounded to 256 (≈8 sigma for uniform dst)
    int avg = (E + B - 1) / B;
    int cap = (avg + avg / 16 + 255) & ~255;

    // ws (4B units): stage[B*cap] | csr[B*cap] | dis[N] | gA[4N] | gB[4N]
    //                | cnt[N] | row_start[N] | gcur[B]
    int*    stage     = (int*)d_ws;
    int*    csr       = stage + (size_t)B * cap;
    float*  dis       = (float*)(csr + (size_t)B * cap);
    __half* gA        = (__half*)(dis + N);
    __half* gB        = (__half*)((int*)gA + (size_t)N * 4);
    int*    cnt       = (int*)gB + (size_t)N * 4;
    int*    row_start = cnt + N;
    int*    gcur      = row_start + N;

    const int BT = 256;
    dim3 thr(BT);
    dim3 blkG(((size_t)N * 8 + BT - 1) / BT);    // gemm1: 8 lanes/node
    dim3 blkA(((size_t)N * 4 + BT - 1) / BT);    // aggregates: 4 lanes/node

    // stage_bin: 512 threads; per_block multiple of 2048 (int4 x 512 alignment)
    int per_block = ((E + 639) / 640 + 2047) & ~2047;
    int SBLK = (E + per_block - 1) / per_block;

    hipMemsetAsync(gcur, 0, (size_t)B * sizeof(int), stream);   // relative cursors
    stage_bin     <<<dim3(SBLK), dim3(512), 0, stream>>>(ei, gcur, stage, E, B, cap, per_block);
    scatter_csr   <<<dim3(B),   dim3(1024), 0, stream>>>(stage, gcur, cap, cnt, dis, row_start, csr, N);
    gemm1         <<<blkG, thr, 0, stream>>>(x, W1, dis, gA, N);
    aggregate_relu<<<blkA, thr, 0, stream>>>(csr, row_start, cnt, dis, b1, gA, gB, N);
    aggregate_out <<<blkA, thr, 0, stream>>>(csr, row_start, cnt, dis, W2, b2, gB, out, N);
}

// Round 9
// 419.829 us; speedup vs baseline: 1.0408x; 1.0408x over previous
//
#include <hip/hip_runtime.h>
#include <hip/hip_fp16.h>

#define F_IN  128
#define F_HID 8
#define F_OUT 16

#define SBSH  9                 // coarse bucket = 512 consecutive dst nodes
#define SBW   (1 << SBSH)
#define MAXB  400               // supports N <= 204800
#define BIN_CAP  32             // LDS entries per bucket (stage_bin)
#define FLUSH_G  16             // flush granularity (16 ints = 64B line)
#define RPT   17                // reg-staged stage entries per thread (cap <= RPT*1024)

// edge_index arrives as int32 [2][E].
// Session laws: (1) scattered 4B global stores/atomics cost ~64B cross-XCD
// writeback -> all scatters are LDS-write-combined contiguous runs;
// (2) gather/scatter kernels need >=2 blocks/CU and plenty of waves;
// (3) fp16 g (3.2MB) is L2-resident per XCD (R8 FETCH decomposition: one
// cold fill per XCD, NO thrash) -> aggregates sit at the per-CU
// outstanding-line wall (R3: three loop shapes all ~74us); (4) single-use
// streams (csr, x, ei) are non-temporal; (5) bucket regions are FIXED-CAP;
// (6) cursor atomics must come from MANY CONCURRENT THREADS; per-wave
// serial atomic chains = 8x blowup, shows as ALL-PIPES-IDLE (R5/R6).
// R8 datum: component sum ~295us vs 437 wall -> ~130us is launch gaps over
// 6 dispatches + scatter_csr's double stage read.
// R9: fuse scatter_csr+gemm1 -> build_gemm. Single-pass stage read
// (reg-staged rv[RPT], static-indexed), local dis feeds the gemm tail,
// gemm x-stream overlaps other blocks' LDS phases. NT store for out.

typedef float f32x4 __attribute__((ext_vector_type(4)));
typedef int   i32x4 __attribute__((ext_vector_type(4)));

// LDS write-combined binning: stage[...] = (src<<9)|(dst&511), bucket-grouped.
// 512 threads/block; NT int4 edge loads; bin_buf slots swizzled (pos+b)&31.
// gcur[b] is RELATIVE fill (memset-0 init); region base = b*cap. (R8-proven)
__global__ __launch_bounds__(512) void stage_bin(const int* __restrict__ ei,
                                                 int* __restrict__ gcur,
                                                 int* __restrict__ stage,
                                                 int E, int B, int cap, int per_block) {
    __shared__ int bin_cnt[MAXB];
    __shared__ int bin_buf[MAXB * BIN_CAP];   // ~50KB
    for (int i = threadIdx.x; i < B; i += blockDim.x) bin_cnt[i] = 0;
    __syncthreads();
    const bool vec = ((E & 3) == 0);
    int base = blockIdx.x * per_block;
    int end  = min(E, base + per_block);
    for (int it = base; it < end; it += (int)blockDim.x * 4) {
        int e = it + (int)threadIdx.x * 4;
        int sv[4], dv[4], m4 = 0;
        if (vec && e + 3 < end) {
            i32x4 s4 = __builtin_nontemporal_load((const i32x4*)(ei + e));
            i32x4 d4 = __builtin_nontemporal_load((const i32x4*)(ei + E + e));
            sv[0] = s4.x; sv[1] = s4.y; sv[2] = s4.z; sv[3] = s4.w;
            dv[0] = d4.x; dv[1] = d4.y; dv[2] = d4.z; dv[3] = d4.w;
            m4 = 4;
        } else {
            for (int q = 0; e + q < end && q < 4; q++) { sv[q] = ei[e + q]; dv[q] = ei[E + e + q]; m4++; }
        }
        for (int q = 0; q < m4; q++) {
            int b   = dv[q] >> SBSH;
            int val = (sv[q] << SBSH) | (dv[q] & (SBW - 1));
            int pos = atomicAdd(&bin_cnt[b], 1);
            if (pos < BIN_CAP) {
                bin_buf[b * BIN_CAP + ((pos + b) & (BIN_CAP - 1))] = val;
            } else {                                  // overflow (rare): direct store
                int gp = b * cap + atomicAdd(&gcur[b], 1);
                stage[gp] = val;
            }
        }
        __syncthreads();
        // flush-NEWEST-16: leftovers [0, c-16) keep slots -> no compaction.
        for (int b2 = threadIdx.x; b2 < B; b2 += blockDim.x) {
            int c = min(bin_cnt[b2], BIN_CAP);
            while (c >= FLUSH_G) {
                int s0 = c - FLUSH_G;
                int r  = b2 * cap + atomicAdd(&gcur[b2], FLUSH_G);
#pragma unroll
                for (int k = 0; k < FLUSH_G; k++)     // 16 independent ds_reads
                    stage[r + k] = bin_buf[b2 * BIN_CAP + ((s0 + k + b2) & (BIN_CAP - 1))];
                c = s0;
            }
            bin_cnt[b2] = c;
        }
        __syncthreads();
    }
    for (int b2 = threadIdx.x; b2 < B; b2 += blockDim.x) {   // final flush (c <= 15)
        int c = min(bin_cnt[b2], BIN_CAP);
        if (c > 0) {
            int r = b2 * cap + atomicAdd(&gcur[b2], c);
            for (int k = 0; k < c; k++)
                stage[r + k] = bin_buf[b2 * BIN_CAP + ((k + b2) & (BIN_CAP - 1))];
        }
    }
}

// ---------------- fused CSR build + layer-1 GEMM ----------------
// one block (1024 thr) per bucket:
//  phase 1: reg-stage bucket entries (rv[RPT], static unroll) + LDS hist
//  phase 2: cnt/dis (also kept in LDS disl) + Hillis-Steele scan -> row_start
//  phase 3: scatter src from REGISTERS into the warm CSR segment
//  phase 4: gemm1 for this bucket's 512 nodes (8 lanes/node, 128B NT reads,
//           W1 transposed in LDS, shfl_xor reduce, lane0 16B store) using
//           the LOCAL dis -- x-stream overlaps other blocks' LDS phases.
__global__ __launch_bounds__(1024) void build_gemm(const int* __restrict__ stage,
                                                   const int* __restrict__ gcur,
                                                   int cap,
                                                   const float* __restrict__ x,
                                                   const float* __restrict__ W1,
                                                   int* __restrict__ cnt,
                                                   float* __restrict__ dis,
                                                   int* __restrict__ row_start,
                                                   int* __restrict__ csr,
                                                   __half* __restrict__ g1, int n) {
    __shared__ int   s0[SBW], s1[SBW];       // 4KB
    __shared__ float w2[F_HID * F_IN];       // 4KB, W1 transposed [f][k]
    __shared__ float disl[SBW];              // 2KB
    int b  = blockIdx.x;
    int nb = b << SBSH;
    int i  = threadIdx.x;                    // 0..1023
    if (i < F_HID * F_IN) {
        int f = i >> 7, k = i & (F_IN - 1);
        w2[i] = W1[k * F_HID + f];
    }
    if (i < SBW) s0[i] = 0;
    __syncthreads();
    int base = b * cap;
    int num  = gcur[b];                      // relative fill count
    // phase 1: single global read of stage, held in registers
    int rv[RPT];
#pragma unroll
    for (int q = 0; q < RPT; q++) {
        int k = i + q * 1024;
        rv[q] = (k < num) ? stage[base + k] : -1;
    }
#pragma unroll
    for (int q = 0; q < RPT; q++)
        if (rv[q] >= 0) atomicAdd(&s0[rv[q] & (SBW - 1)], 1);
    for (int k = RPT * 1024 + i; k < num; k += 1024)          // safety residual
        atomicAdd(&s0[stage[base + k] & (SBW - 1)], 1);
    __syncthreads();
    // phase 2: cnt/dis + scan
    int c = (i < SBW) ? s0[i] : 0;
    if (i < SBW && nb + i < n) {
        cnt[nb + i] = c;
        float dv = rsqrtf((float)(c + 1));
        dis[nb + i] = dv;
        disl[i] = dv;
    }
    int* src = s0; int* dst = s1;
    for (int off = 1; off < SBW; off <<= 1) {       // Hillis-Steele inclusive scan
        if (i < SBW) dst[i] = src[i] + ((i >= off) ? src[i - off] : 0);
        __syncthreads();
        int* t = src; src = dst; dst = t;
    }
    if (i < SBW) {
        int e = base + src[i] - c;                   // exclusive scan
        if (nb + i < n) row_start[nb + i] = e;
        dst[i] = e;                                  // dst becomes the cursor array
    }
    __syncthreads();
    // phase 3: scatter from registers (concurrent LDS cursor atomics, law 6)
#pragma unroll
    for (int q = 0; q < RPT; q++) {
        if (rv[q] >= 0) {
            int v = rv[q];
            int pos = atomicAdd(&dst[v & (SBW - 1)], 1);
            csr[pos] = v >> SBSH;
        }
    }
    for (int k = RPT * 1024 + i; k < num; k += 1024) {        // safety residual
        int v = stage[base + k];
        int pos = atomicAdd(&dst[v & (SBW - 1)], 1);
        csr[pos] = v >> SBSH;
    }
    __syncthreads();
    // phase 4: gemm for this bucket's nodes
    int g = i >> 3, l = i & 7;               // 128 groups of 8 lanes
#pragma unroll
    for (int j = 0; j < 4; j++) {
        int ln   = j * 128 + g;              // local node 0..511
        int node = nb + ln;
        if (node >= n) continue;
        const f32x4* xr = (const f32x4*)(x + (size_t)node * F_IN);
        float acc[F_HID];
#pragma unroll
        for (int f = 0; f < F_HID; f++) acc[f] = 0.0f;
#pragma unroll
        for (int it = 0; it < 4; it++) {
            int jj = l + it * 8;             // this lane's float4 index
            f32x4 v = __builtin_nontemporal_load(xr + jj);
#pragma unroll
            for (int f = 0; f < F_HID; f++) {
                const float* wf = &w2[f * F_IN + jj * 4];
                acc[f] += v[0] * wf[0] + v[1] * wf[1] + v[2] * wf[2] + v[3] * wf[3];
            }
        }
#pragma unroll
        for (int f = 0; f < F_HID; f++) {    // reduce across the 8 lanes
            acc[f] += __shfl_xor(acc[f], 1);
            acc[f] += __shfl_xor(acc[f], 2);
            acc[f] += __shfl_xor(acc[f], 4);
        }
        if (l == 0) {
            float d = disl[ln];
            __half2 h[4];
#pragma unroll
            for (int p = 0; p < 4; p++) h[p] = __floats2half2_rn(acc[2 * p] * d, acc[2 * p + 1] * d);
            *(uint4*)(g1 + (size_t)node * F_HID) = *(uint4*)h;   // 16B store
        }
    }
}

// ---------------- layer-1 aggregate + bias + ReLU + xdis -> g2 (fp16) ----------------
// 4 lanes/node, lane l owns features {2l,2l+1} as one half2 (unchanged from R4).
__global__ __launch_bounds__(256) void aggregate_relu(const int* __restrict__ csr,
                                                      const int* __restrict__ row_start,
                                                      const int* __restrict__ cnt,
                                                      const float* __restrict__ dis,
                                                      const float* __restrict__ b1,
                                                      const __half* __restrict__ gin,
                                                      __half* __restrict__ gout, int n) {
    int t = blockIdx.x * blockDim.x + threadIdx.x;
    int node = t >> 2;
    int l = t & 3;
    if (node >= n) return;
    const __half2* g2 = (const __half2*)gin;      // half2 index = src*4 + l
    int beg = row_start[node];
    int c   = cnt[node];
    float2 acc = __half22float2(g2[(unsigned)node * 4 + l]);   // self-loop
    int j = 0;
    int cm8 = c & ~7;
    for (; j < cm8; j += 8) {
        int va = __builtin_nontemporal_load(csr + beg + j + l);
        int vb = __builtin_nontemporal_load(csr + beg + j + 4 + l);
        int s0 = __shfl(va, 0, 4), s1 = __shfl(va, 1, 4);
        int s2 = __shfl(va, 2, 4), s3 = __shfl(va, 3, 4);
        int s4 = __shfl(vb, 0, 4), s5 = __shfl(vb, 1, 4);
        int s6 = __shfl(vb, 2, 4), s7 = __shfl(vb, 3, 4);
        __half2 h0 = g2[(unsigned)s0 * 4 + l];    // 8 independent 4B gathers
        __half2 h1 = g2[(unsigned)s1 * 4 + l];
        __half2 h2 = g2[(unsigned)s2 * 4 + l];
        __half2 h3 = g2[(unsigned)s3 * 4 + l];
        __half2 h4 = g2[(unsigned)s4 * 4 + l];
        __half2 h5 = g2[(unsigned)s5 * 4 + l];
        __half2 h6 = g2[(unsigned)s6 * 4 + l];
        __half2 h7 = g2[(unsigned)s7 * 4 + l];
        float2 f0 = __half22float2(h0), f1 = __half22float2(h1);
        float2 f2 = __half22float2(h2), f3 = __half22float2(h3);
        float2 f4 = __half22float2(h4), f5 = __half22float2(h5);
        float2 f6 = __half22float2(h6), f7 = __half22float2(h7);
        acc.x += ((f0.x + f1.x) + (f2.x + f3.x)) + ((f4.x + f5.x) + (f6.x + f7.x));
        acc.y += ((f0.y + f1.y) + (f2.y + f3.y)) + ((f4.y + f5.y) + (f6.y + f7.y));
    }
    for (; j < c; j++) {
        int s = __builtin_nontemporal_load(csr + beg + j);
        float2 a = __half22float2(g2[(unsigned)s * 4 + l]);
        acc.x += a.x; acc.y += a.y;
    }
    float d = dis[node];
    float2 bv = *(const float2*)(b1 + 2 * l);
    float rx = fmaxf(fmaf(acc.x, d, bv.x), 0.0f) * d;
    float ry = fmaxf(fmaf(acc.y, d, bv.y), 0.0f) * d;
    ((__half2*)gout)[(unsigned)node * 4 + l] = __floats2half2_rn(rx, ry);  // 256B/wave
}

// ---------------- layer-2 aggregate + W2/b2 -> out ----------------
__global__ __launch_bounds__(256) void aggregate_out(const int* __restrict__ csr,
                                                     const int* __restrict__ row_start,
                                                     const int* __restrict__ cnt,
                                                     const float* __restrict__ dis,
                                                     const float* __restrict__ W2,
                                                     const float* __restrict__ b2,
                                                     const __half* __restrict__ gin,
                                                     float* __restrict__ out, int n) {
    int t = blockIdx.x * blockDim.x + threadIdx.x;
    int node = t >> 2;
    int l = t & 3;
    if (node >= n) return;
    const __half2* g2 = (const __half2*)gin;
    int beg = row_start[node];
    int c   = cnt[node];
    float2 acc = __half22float2(g2[(unsigned)node * 4 + l]);   // self-loop
    int j = 0;
    int cm8 = c & ~7;
    for (; j < cm8; j += 8) {
        int va = __builtin_nontemporal_load(csr + beg + j + l);
        int vb = __builtin_nontemporal_load(csr + beg + j + 4 + l);
        int s0 = __shfl(va, 0, 4), s1 = __shfl(va, 1, 4);
        int s2 = __shfl(va, 2, 4), s3 = __shfl(va, 3, 4);
        int s4 = __shfl(vb, 0, 4), s5 = __shfl(vb, 1, 4);
        int s6 = __shfl(vb, 2, 4), s7 = __shfl(vb, 3, 4);
        __half2 h0 = g2[(unsigned)s0 * 4 + l];
        __half2 h1 = g2[(unsigned)s1 * 4 + l];
        __half2 h2 = g2[(unsigned)s2 * 4 + l];
        __half2 h3 = g2[(unsigned)s3 * 4 + l];
        __half2 h4 = g2[(unsigned)s4 * 4 + l];
        __half2 h5 = g2[(unsigned)s5 * 4 + l];
        __half2 h6 = g2[(unsigned)s6 * 4 + l];
        __half2 h7 = g2[(unsigned)s7 * 4 + l];
        float2 f0 = __half22float2(h0), f1 = __half22float2(h1);
        float2 f2 = __half22float2(h2), f3 = __half22float2(h3);
        float2 f4 = __half22float2(h4), f5 = __half22float2(h5);
        float2 f6 = __half22float2(h6), f7 = __half22float2(h7);
        acc.x += ((f0.x + f1.x) + (f2.x + f3.x)) + ((f4.x + f5.x) + (f6.x + f7.x));
        acc.y += ((f0.y + f1.y) + (f2.y + f3.y)) + ((f4.y + f5.y) + (f6.y + f7.y));
    }
    for (; j < c; j++) {
        int s = __builtin_nontemporal_load(csr + beg + j);
        float2 a = __half22float2(g2[(unsigned)s * 4 + l]);
        acc.x += a.x; acc.y += a.y;
    }
    float d = dis[node];
    float ax = acc.x * d, ay = acc.y * d;         // a[2l], a[2l+1]
    float4 o = ((const float4*)b2)[l];            // outputs 4l..4l+3
#pragma unroll
    for (int s = 0; s < 4; s++) {
        float axs = __shfl(ax, s, 4);             // a[2s]
        float ays = __shfl(ay, s, 4);             // a[2s+1]
        float4 w0 = ((const float4*)W2)[(2 * s) * 4 + l];       // W2[2s][4l..4l+3]
        float4 w1 = ((const float4*)W2)[(2 * s + 1) * 4 + l];   // W2[2s+1][4l..4l+3]
        o.x = fmaf(axs, w0.x, fmaf(ays, w1.x, o.x));
        o.y = fmaf(axs, w0.y, fmaf(ays, w1.y, o.y));
        o.z = fmaf(axs, w0.z, fmaf(ays, w1.z, o.z));
        o.w = fmaf(axs, w0.w, fmaf(ays, w1.w, o.w));
    }
    // NT store: out is never re-read; don't evict gin's L2 lines
    f32x4 ov = {o.x, o.y, o.z, o.w};
    __builtin_nontemporal_store(ov, (f32x4*)(out + (size_t)node * F_OUT + 4 * l));
}

extern "C" void kernel_launch(void* const* d_in, const int* in_sizes, int n_in,
                              void* d_out, int out_size, void* d_ws, size_t ws_size,
                              hipStream_t stream) {
    const float* x  = (const float*)d_in[0];
    const int*   ei = (const int*)d_in[1];
    const float* W1 = (const float*)d_in[2];
    const float* b1 = (const float*)d_in[3];
    const float* W2 = (const float*)d_in[4];
    const float* b2 = (const float*)d_in[5];
    float* out = (float*)d_out;

    const int N = in_sizes[0] / F_IN;
    const int E = in_sizes[1] / 2;
    const int B = (N + SBW - 1) >> SBSH;   // 391 for N=200000

    // fixed bucket capacity: avg + ~6%, rounded to 256 (≈8 sigma for uniform dst)
    int avg = (E + B - 1) / B;
    int cap = (avg + avg / 16 + 255) & ~255;

    // ws (4B units): stage[B*cap] | csr[B*cap] | dis[N] | gA[4N] | gB[4N]
    //                | cnt[N] | row_start[N] | gcur[B]
    int*    stage     = (int*)d_ws;
    int*    csr       = stage + (size_t)B * cap;
    float*  dis       = (float*)(csr + (size_t)B * cap);
    __half* gA        = (__half*)(dis + N);
    __half* gB        = (__half*)((int*)gA + (size_t)N * 4);
    int*    cnt       = (int*)gB + (size_t)N * 4;
    int*    row_start = cnt + N;
    int*    gcur      = row_start + N;

    const int BT = 256;
    dim3 thr(BT);
    dim3 blkA(((size_t)N * 4 + BT - 1) / BT);    // aggregates: 4 lanes/node

    // stage_bin: 512 threads; per_block multiple of 2048 (int4 x 512 alignment)
    int per_block = ((E + 639) / 640 + 2047) & ~2047;
    int SBLK = (E + per_block - 1) / per_block;

    hipMemsetAsync(gcur, 0, (size_t)B * sizeof(int), stream);   // relative cursors
    stage_bin     <<<dim3(SBLK), dim3(512), 0, stream>>>(ei, gcur, stage, E, B, cap, per_block);
    build_gemm    <<<dim3(B), dim3(1024), 0, stream>>>(stage, gcur, cap, x, W1,
                                                       cnt, dis, row_start, csr, gA, N);
    aggregate_relu<<<blkA, thr, 0, stream>>>(csr, row_start, cnt, dis, b1, gA, gB, N);
    aggregate_out <<<blkA, thr, 0, stream>>>(csr, row_start, cnt, dis, W2, b2, gB, out, N);
}